// Round 1
// 1086.534 us; speedup vs baseline: 1.0753x; 1.0753x over previous
//
#include <hip/hip_runtime.h>
#include <math.h>

#define BB 4
#define HHH 128
#define WWW 128
#define AANG 96
#define DDET 128
#define TSTEP 182
#define M_P (BB*HHH*WWW)   // 65536
#define M_D (BB*AANG*DDET) // 49152
#define INV_OPN (1.0f/128.0f)

typedef __bf16 bf16x8 __attribute__((ext_vector_type(8)));
typedef float  f32x4  __attribute__((ext_vector_type(4)));

__device__ __forceinline__ void split_store(__bf16* hi, __bf16* lo, int off, float v) {
    __bf16 h = (__bf16)v;
    hi[off] = h;
    lo[off] = (__bf16)(v - (float)h);
}

// ================= conv core: implicit GEMM, 16x16x32 bf16 MFMA, bf16x3 split =================
// A: [M][CIP] activations (hi/lo), pixels linear over [B, IH, 128]
// W: [taps_pad][COP][CIP] transposed weights (hi/lo), zero-padded
// K enumerated tap-major: k = tap*CIP + ci. CIP=32 -> chunk==tap; CIP=8 -> chunk covers 4 taps.
template<int CIP, int NCH, int NCOT, int IH>
__device__ __forceinline__ void conv_core(
        const __bf16* __restrict__ Ahi, const __bf16* __restrict__ Alo,
        const __bf16* __restrict__ Whi, const __bf16* __restrict__ Wlo,
        int mtile, f32x4 acc[NCOT])
{
    const int IW = 128;
    const int COP = NCOT * 16;
    int lane = threadIdx.x & 63;
    int n16  = lane & 15;
    int quad = lane >> 4;
    int p0  = mtile * 16;
    int b   = p0 / (IH * IW);
    int rem = p0 - b * (IH * IW);
    int ty  = rem >> 7;
    int tx0 = rem & 127;
    #pragma unroll
    for (int c = 0; c < NCH; ++c) {
        int tap = (CIP == 32) ? c : (c * 4 + quad);
        int dy = tap / 3 - 1;
        int dx = tap % 3 - 1;
        int yy = ty + dy;
        int xx = tx0 + n16 + dx;
        bool valid = (tap < 9) && (yy >= 0) && (yy < IH) && (xx >= 0) && (xx < IW);
        bf16x8 a_h = {};
        bf16x8 a_l = {};
        if (valid) {
            size_t off = (size_t)(b * IH * IW + yy * IW + xx) * CIP
                       + ((CIP == 32) ? (quad * 8) : 0);
            a_h = *(const bf16x8*)(Ahi + off);
            a_l = *(const bf16x8*)(Alo + off);
        }
        #pragma unroll
        for (int ct = 0; ct < NCOT; ++ct) {
            size_t woff = ((size_t)tap * COP + ct * 16 + n16) * CIP
                        + ((CIP == 32) ? (quad * 8) : 0);
            bf16x8 b_h = *(const bf16x8*)(Whi + woff);
            bf16x8 b_l = *(const bf16x8*)(Wlo + woff);
            acc[ct] = __builtin_amdgcn_mfma_f32_16x16x32_bf16(a_h, b_h, acc[ct], 0, 0, 0);
            acc[ct] = __builtin_amdgcn_mfma_f32_16x16x32_bf16(a_h, b_l, acc[ct], 0, 0, 0);
            acc[ct] = __builtin_amdgcn_mfma_f32_16x16x32_bf16(a_l, b_h, acc[ct], 0, 0, 0);
        }
    }
}

// conv1 / conv2: bias + relu -> hid hi/lo [M][32]
template<int CIP, int NCH, int IH>
__global__ __launch_bounds__(256) void conv_ab_k(
        const __bf16* __restrict__ Ahi, const __bf16* __restrict__ Alo,
        const __bf16* __restrict__ Whi, const __bf16* __restrict__ Wlo,
        const float* __restrict__ bias,
        __bf16* __restrict__ Ohi, __bf16* __restrict__ Olo, int Mtiles)
{
    int wid = (blockIdx.x * 256 + threadIdx.x) >> 6;
    if (wid >= Mtiles) return;
    f32x4 acc[2] = {};
    conv_core<CIP, NCH, 2, IH>(Ahi, Alo, Whi, Wlo, wid, acc);
    int lane = threadIdx.x & 63;
    int n16 = lane & 15;
    int quad = lane >> 4;
    #pragma unroll
    for (int ct = 0; ct < 2; ++ct) {
        float bv = bias[ct * 16 + n16];
        #pragma unroll
        for (int r = 0; r < 4; ++r) {
            float v = acc[ct][r] + bv;
            v = fmaxf(v, 0.f);
            int m = wid * 16 + quad * 4 + r;
            split_store(Ohi, Olo, m * 32 + ct * 16 + n16, v);
        }
    }
}

// conv3 dual: dual_f += sigma*(acc+bias); write cat_d ch0-4 hi/lo; dual0 packed (co==0)
template<int IH>
__global__ __launch_bounds__(256) void conv_c_dual_k(
        const __bf16* __restrict__ Ahi, const __bf16* __restrict__ Alo,
        const __bf16* __restrict__ Whi, const __bf16* __restrict__ Wlo,
        const float* __restrict__ bias, const float* __restrict__ sigma_p,
        float* __restrict__ dual_f, __bf16* __restrict__ cat_hi, __bf16* __restrict__ cat_lo,
        float* __restrict__ dual0, int Mtiles)
{
    int wid = (blockIdx.x * 256 + threadIdx.x) >> 6;
    if (wid >= Mtiles) return;
    f32x4 acc[1] = {};
    conv_core<32, 9, 1, IH>(Ahi, Alo, Whi, Wlo, wid, acc);
    int lane = threadIdx.x & 63;
    int n16 = lane & 15;
    int quad = lane >> 4;
    if (n16 < 5) {
        float sg = *sigma_p;
        float bv = bias[n16];
        #pragma unroll
        for (int r = 0; r < 4; ++r) {
            int m = wid * 16 + quad * 4 + r;
            float v = acc[0][r] + bv;
            float dn = dual_f[m * 5 + n16] + sg * v;
            dual_f[m * 5 + n16] = dn;
            split_store(cat_hi, cat_lo, m * 8 + n16, dn);
            if (n16 == 0) dual0[m] = dn;
        }
    }
}

// conv3 primal: primal update + pbar ch1
template<int IH>
__global__ __launch_bounds__(256) void conv_c_prim_k(
        const __bf16* __restrict__ Ahi, const __bf16* __restrict__ Alo,
        const __bf16* __restrict__ Whi, const __bf16* __restrict__ Wlo,
        const float* __restrict__ bias, const float* __restrict__ tau_p,
        const float* __restrict__ theta_p,
        float* __restrict__ primal_f, __bf16* __restrict__ cat_hi, __bf16* __restrict__ cat_lo,
        float* __restrict__ pbar1, int Mtiles)
{
    int wid = (blockIdx.x * 256 + threadIdx.x) >> 6;
    if (wid >= Mtiles) return;
    f32x4 acc[1] = {};
    conv_core<32, 9, 1, IH>(Ahi, Alo, Whi, Wlo, wid, acc);
    int lane = threadIdx.x & 63;
    int n16 = lane & 15;
    int quad = lane >> 4;
    if (n16 < 5) {
        float ta = *tau_p;
        float th = *theta_p;
        float bv = bias[n16];
        #pragma unroll
        for (int r = 0; r < 4; ++r) {
            int m = wid * 16 + quad * 4 + r;
            float v = acc[0][r] + bv;
            float pold = primal_f[m * 5 + n16];
            float pn = pold + ta * v;
            primal_f[m * 5 + n16] = pn;
            split_store(cat_hi, cat_lo, m * 8 + n16, pn);
            if (n16 == 1) pbar1[m] = pn + th * (pn - pold);
        }
    }
}

// ================= Radon forward: fused t-split x4 + LDS reduce + direct cat store ========
// block = 256 threads = 4 waves; wave q handles t-quarter q of 64 consecutive outputs.
// Analytic t-clipping: contribution is exactly 0 unless xi in (-1,128) and yi in (-1,128).
__global__ __launch_bounds__(256) void radon_fwd_fused_k(const float* __restrict__ img,
                                                         const float* __restrict__ trig,
                                                         __bf16* __restrict__ cat_hi,
                                                         __bf16* __restrict__ cat_lo)
{
    __shared__ float red[256];
    int tid = threadIdx.x;
    int q = tid >> 6;
    int j = tid & 63;
    int pix = blockIdx.x * 64 + j;
    int d = pix & 127;
    int b = pix / (AANG * DDET);
    int a = (pix - b * AANG * DDET) >> 7;
    float c  = trig[a];
    float sn = trig[AANG + a];
    float s = (float)d - 63.5f;
    float A = s * c + 63.5f;    // xi = A - t*sn
    float C = s * sn + 63.5f;   // yi = C + t*c
    // valid-t interval (outside -> contribution exactly 0)
    float tlo = -1e30f, thi = 1e30f;
    if (sn > 1e-6f) {
        tlo = (A - 128.f) / sn;
        thi = (A + 1.f) / sn;
    }
    if (c > 1e-6f) {
        tlo = fmaxf(tlo, (-1.f - C) / c);
        thi = fminf(thi, (128.f - C) / c);
    } else if (c < -1e-6f) {
        tlo = fmaxf(tlo, (128.f - C) / c);
        thi = fminf(thi, (-1.f - C) / c);
    }
    // convert to tt index range with +-1 safety margin (extra steps are exact zeros)
    float flo = fmaxf(fminf(tlo + 90.5f, 300.f), -300.f);
    float fhi = fmaxf(fminf(thi + 90.5f, 300.f), -300.f);
    int clo = (int)floorf(flo) - 1;
    int chi = (int)floorf(fhi) + 2;
    int t0 = q * 46;
    int t1 = t0 + 46 < TSTEP ? t0 + 46 : TSTEP;
    if (clo > t0) t0 = clo;
    if (chi < t1) t1 = chi;
    const float* ib = img + b * (HHH * WWW);
    float acc = 0.f;
    for (int tt = t0; tt < t1; ++tt) {
        float t = (float)tt - 90.5f;
        float xi = A - t * sn;
        float yi = C + t * c;
        float x0f = floorf(xi), y0f = floorf(yi);
        float wx = xi - x0f, wy = yi - y0f;
        int x0 = (int)x0f, y0 = (int)y0f;
        int x1 = x0 + 1, y1 = y0 + 1;
        bool xv0 = (x0 >= 0) & (x0 < WWW);
        bool xv1 = (x1 >= 0) & (x1 < WWW);
        bool yv0 = (y0 >= 0) & (y0 < HHH);
        bool yv1 = (y1 >= 0) & (y1 < HHH);
        float v00 = (yv0 & xv0) ? ib[y0 * WWW + x0] : 0.f;
        float v01 = (yv0 & xv1) ? ib[y0 * WWW + x1] : 0.f;
        float v10 = (yv1 & xv0) ? ib[y1 * WWW + x0] : 0.f;
        float v11 = (yv1 & xv1) ? ib[y1 * WWW + x1] : 0.f;
        acc += v00 * (1.f - wy) * (1.f - wx) + v01 * (1.f - wy) * wx
             + v10 * wy * (1.f - wx) + v11 * wy * wx;
    }
    red[tid] = acc;
    __syncthreads();
    if (tid < 64) {
        int p2 = blockIdx.x * 64 + tid;
        float v = (red[tid] + red[tid + 64] + red[tid + 128] + red[tid + 192]) * INV_OPN;
        split_store(cat_hi, cat_lo, p2 * 8 + 5, v);
    }
}

// ================= Radon adjoint: fused a-split x2 + LDS reduce + direct cat store ========
// block = 256 threads = 128 pixels x 2 angle-halves; trig from precomputed table.
__global__ __launch_bounds__(256) void radon_adj_fused_k(const float* __restrict__ sino0,
                                                         const float* __restrict__ trig,
                                                         __bf16* __restrict__ cat_hi,
                                                         __bf16* __restrict__ cat_lo)
{
    __shared__ float cs[AANG], ss[AANG];
    __shared__ float red[256];
    int tid = threadIdx.x;
    if (tid < AANG) {
        cs[tid] = trig[tid];
        ss[tid] = trig[AANG + tid];
    }
    __syncthreads();
    int h = tid >> 7;
    int j = tid & 127;
    int pix = blockIdx.x * 128 + j;
    int x = pix & 127;
    int yv = (pix >> 7) & 127;
    int b = pix >> 14;
    float px = (float)x - 63.5f;
    float py = (float)yv - 63.5f;
    const float* sb = sino0 + b * (AANG * DDET);
    float acc = 0.f;
    int a0 = h * 48;
    for (int a = a0; a < a0 + 48; ++a) {
        float det = px * cs[a] + py * ss[a] + 63.5f;
        float dh = floorf(det);
        float w = det - dh;
        int d0 = (int)dh;
        int d1 = d0 + 1;
        float v0 = (d0 >= 0 && d0 < DDET) ? sb[a * DDET + d0] : 0.f;
        float v1 = (d1 >= 0 && d1 < DDET) ? sb[a * DDET + d1] : 0.f;
        acc += v0 * (1.f - w) + v1 * w;
    }
    red[tid] = acc;
    __syncthreads();
    if (tid < 128) {
        float v = (red[tid] + red[tid + 128]) * INV_OPN;
        split_store(cat_hi, cat_lo, (blockIdx.x * 128 + tid) * 8 + 5, v);
    }
}

// ================= setup: trig table + weight transpose/split + y cat store ===============
__global__ __launch_bounds__(256) void prep_all_k(
        const float* __restrict__ dw1, const float* __restrict__ dw2, const float* __restrict__ dw3,
        const float* __restrict__ pw1, const float* __restrict__ pw2, const float* __restrict__ pw3,
        const float* __restrict__ y,
        __bf16* __restrict__ wT, float* __restrict__ trig,
        __bf16* __restrict__ cat_d_hi, __bf16* __restrict__ cat_d_lo)
{
    __bf16* d1h = wT;            __bf16* d1l = d1h + 3072;
    __bf16* d2h = d1l + 3072;    __bf16* d2l = d2h + 9216;
    __bf16* d3h = d2l + 9216;    __bf16* d3l = d3h + 4608;
    __bf16* p1h = d3l + 4608;    __bf16* p1l = p1h + 3072;
    __bf16* p2h = p1l + 3072;    __bf16* p2l = p2h + 9216;
    __bf16* p3h = p2l + 9216;    __bf16* p3l = p3h + 4608;
    int i = blockIdx.x * 256 + threadIdx.x;
    if (i < AANG) {                 // trig table (double precision, matches previous behavior)
        double ang = (double)i * M_PI / (double)AANG;
        trig[i] = (float)cos(ang);
        trig[AANG + i] = (float)sin(ang);
        return;
    }
    i -= AANG;
    if (i < 2016) {                 // dw1: CI=7 CO=32 -> [12][32][8]
        int co = i & 31; int r = i >> 5; int ci = r % 7; int tap = r / 7;
        split_store(d1h, d1l, (tap * 32 + co) * 8 + ci, dw1[i]);
        return;
    }
    i -= 2016;
    if (i < 9216) {                 // dw2: CI=32 CO=32 -> [9][32][32]
        int co = i & 31; int r = i >> 5; int ci = r & 31; int tap = r >> 5;
        split_store(d2h, d2l, (tap * 32 + co) * 32 + ci, dw2[i]);
        return;
    }
    i -= 9216;
    if (i < 1440) {                 // dw3: CI=32 CO=5 -> [9][16][32]
        int co = i % 5; int r = i / 5; int ci = r & 31; int tap = r >> 5;
        split_store(d3h, d3l, (tap * 16 + co) * 32 + ci, dw3[i]);
        return;
    }
    i -= 1440;
    if (i < 1728) {                 // pw1: CI=6 CO=32 -> [12][32][8]
        int co = i & 31; int r = i >> 5; int ci = r % 6; int tap = r / 6;
        split_store(p1h, p1l, (tap * 32 + co) * 8 + ci, pw1[i]);
        return;
    }
    i -= 1728;
    if (i < 9216) {                 // pw2
        int co = i & 31; int r = i >> 5; int ci = r & 31; int tap = r >> 5;
        split_store(p2h, p2l, (tap * 32 + co) * 32 + ci, pw2[i]);
        return;
    }
    i -= 9216;
    if (i < 1440) {                 // pw3
        int co = i % 5; int r = i / 5; int ci = r & 31; int tap = r >> 5;
        split_store(p3h, p3l, (tap * 16 + co) * 32 + ci, pw3[i]);
        return;
    }
    i -= 1440;
    if (i < M_D) {                  // y -> cat_d ch6
        split_store(cat_d_hi, cat_d_lo, i * 8 + 6, y[i]);
        return;
    }
}

__global__ __launch_bounds__(256) void extract_k(const float* __restrict__ primal_f,
                                                 float* __restrict__ out)
{
    int pix = blockIdx.x * 256 + threadIdx.x;
    if (pix >= M_P) return;
    out[pix] = primal_f[pix * 5];
}

extern "C" void kernel_launch(void* const* d_in, const int* in_sizes, int n_in,
                              void* d_out, int out_size, void* d_ws, size_t ws_size,
                              hipStream_t stream) {
    const float* y     = (const float*)d_in[0];
    const float* sigma = (const float*)d_in[1];
    const float* tau   = (const float*)d_in[2];
    const float* theta = (const float*)d_in[3];
    const float* dw1 = (const float*)d_in[4];
    const float* db1 = (const float*)d_in[5];
    const float* dw2 = (const float*)d_in[6];
    const float* db2 = (const float*)d_in[7];
    const float* dw3 = (const float*)d_in[8];
    const float* db3 = (const float*)d_in[9];
    const float* pw1 = (const float*)d_in[10];
    const float* pb1 = (const float*)d_in[11];
    const float* pw2 = (const float*)d_in[12];
    const float* pb2 = (const float*)d_in[13];
    const float* pw3 = (const float*)d_in[14];
    const float* pb3 = (const float*)d_in[15];

    // ---- workspace layout: zeroed region first (single memset), then live buffers ----
    // Z0 (float, zeroed): primal_f M_P*5 | dual_f M_D*5 | pbar1 M_P      = 638976 f
    // Z1 (bf16, zeroed):  cat_d hi/lo M_D*8 ea | cat_p hi/lo M_P*8 ea | wT 67584
    // then: trig 192 f | dual0 M_D f | hidA/hidB hi/lo M_P*32 ea
    float* ws = (float*)d_ws;
    float* primal_f = ws;                    // M_P*5
    float* dual_f   = primal_f + M_P * 5;    // M_D*5
    float* pbar1    = dual_f + M_D * 5;      // M_P
    __bf16* bf = (__bf16*)(pbar1 + M_P);
    __bf16* cat_d_hi = bf;                   // M_D*8
    __bf16* cat_d_lo = cat_d_hi + M_D * 8;
    __bf16* cat_p_hi = cat_d_lo + M_D * 8;   // M_P*8
    __bf16* cat_p_lo = cat_p_hi + M_P * 8;
    __bf16* wT       = cat_p_lo + M_P * 8;   // 67584
    float* trig     = (float*)(wT + 67584);  // 192
    float* dual0    = trig + 192;            // M_D
    __bf16* hidA_hi = (__bf16*)(dual0 + M_D);
    __bf16* hidA_lo = hidA_hi + M_P * 32;
    __bf16* hidB_hi = hidA_lo + M_P * 32;
    __bf16* hidB_lo = hidB_hi + M_P * 32;

    __bf16* d1h = wT;            __bf16* d1l = d1h + 3072;
    __bf16* d2h = d1l + 3072;    __bf16* d2l = d2h + 9216;
    __bf16* d3h = d2l + 9216;    __bf16* d3l = d3h + 4608;
    __bf16* p1h = d3l + 4608;    __bf16* p1l = p1h + 3072;
    __bf16* p2h = p1l + 3072;    __bf16* p2l = p2h + 9216;
    __bf16* p3h = p2l + 9216;    __bf16* p3l = p3h + 4608;

    // single contiguous memset: fp32 state + cat pads + weight pads
    size_t zbytes = (size_t)(M_P * 5 + M_D * 5 + M_P) * 4
                  + (size_t)(M_D * 16 + M_P * 16 + 67584) * 2;
    hipMemsetAsync(ws, 0, zbytes, stream);

    // setup: trig + weights + y (one kernel)
    {
        int items = AANG + 25056 + M_D;
        prep_all_k<<<(items + 255) / 256, 256, 0, stream>>>(dw1, dw2, dw3, pw1, pw2, pw3, y,
                                                            wT, trig, cat_d_hi, cat_d_lo);
    }

    const int MT_D = M_D / 16;   // 3072
    const int MT_P = M_P / 16;   // 4096

    for (int it = 0; it < 10; ++it) {
        radon_fwd_fused_k<<<M_D / 64, 256, 0, stream>>>(pbar1, trig, cat_d_hi, cat_d_lo);
        conv_ab_k<8, 3, AANG><<<MT_D / 4, 256, 0, stream>>>(cat_d_hi, cat_d_lo, d1h, d1l, db1, hidA_hi, hidA_lo, MT_D);
        conv_ab_k<32, 9, AANG><<<MT_D / 4, 256, 0, stream>>>(hidA_hi, hidA_lo, d2h, d2l, db2, hidB_hi, hidB_lo, MT_D);
        conv_c_dual_k<AANG><<<MT_D / 4, 256, 0, stream>>>(hidB_hi, hidB_lo, d3h, d3l, db3, sigma, dual_f, cat_d_hi, cat_d_lo, dual0, MT_D);
        radon_adj_fused_k<<<M_P / 128, 256, 0, stream>>>(dual0, trig, cat_p_hi, cat_p_lo);
        conv_ab_k<8, 3, HHH><<<MT_P / 4, 256, 0, stream>>>(cat_p_hi, cat_p_lo, p1h, p1l, pb1, hidA_hi, hidA_lo, MT_P);
        conv_ab_k<32, 9, HHH><<<MT_P / 4, 256, 0, stream>>>(hidA_hi, hidA_lo, p2h, p2l, pb2, hidB_hi, hidB_lo, MT_P);
        conv_c_prim_k<HHH><<<MT_P / 4, 256, 0, stream>>>(hidB_hi, hidB_lo, p3h, p3l, pb3, tau, theta, primal_f, cat_p_hi, cat_p_lo, pbar1, MT_P);
    }
    extract_k<<<M_P / 256, 256, 0, stream>>>(primal_f, (float*)d_out);
}

// Round 3
// 975.313 us; speedup vs baseline: 1.1979x; 1.1140x over previous
//
#include <hip/hip_runtime.h>
#include <math.h>

#define BB 4
#define HHH 128
#define WWW 128
#define AANG 96
#define DDET 128
#define TSTEP 182
#define M_P (BB*HHH*WWW)   // 65536
#define M_D (BB*AANG*DDET) // 49152
#define INV_OPN (1.0f/128.0f)

typedef __bf16 bf16x8 __attribute__((ext_vector_type(8)));
typedef float  f32x4  __attribute__((ext_vector_type(4)));

__device__ __forceinline__ void split_store(__bf16* hi, __bf16* lo, int off, float v) {
    __bf16 h = (__bf16)v;
    hi[off] = h;
    lo[off] = (__bf16)(v - (float)h);
}

// ================= weight staging: global [tap][co][ci] -> LDS fragment order =============
// Fragment order: for CIP=32: [ct][tap][lane(=quad*16+n16)] x 8 elems  -> a wave's read of one
// (tap,ct) chunk is a contiguous 1KB (conflict-free ds_read_b128).
// For CIP=8: [ct][tap(0..4*NCH)][n16] x 8 elems -> each 16-lane quarter reads contiguous 256B.
template<int CIP, int NCH, int NCOT>
__device__ __forceinline__ void stage_w(const __bf16* __restrict__ Whi,
                                        const __bf16* __restrict__ Wlo,
                                        __bf16* sWh, __bf16* sWl)
{
    constexpr int NTAP = (CIP == 32) ? NCH : NCH * 4;
    constexpr int COP  = NCOT * 16;
    constexpr int TOT8 = NCOT * NTAP * ((CIP == 32) ? 64 : 16);
    for (int i8 = threadIdx.x; i8 < TOT8; i8 += 256) {
        int src8;
        if (CIP == 32) {
            int n16 = i8 & 15; int quad = (i8 >> 4) & 3;
            int tc = i8 >> 6; int tap = tc % NTAP; int ct = tc / NTAP;
            src8 = (tap * COP + ct * 16 + n16) * 4 + quad;
        } else {
            int n16 = i8 & 15;
            int tc = i8 >> 4; int tap = tc % NTAP; int ct = tc / NTAP;
            src8 = (tap * COP + ct * 16 + n16);
        }
        *(bf16x8*)(sWh + i8 * 8) = *(const bf16x8*)(Whi + src8 * 8);
        *(bf16x8*)(sWl + i8 * 8) = *(const bf16x8*)(Wlo + src8 * 8);
    }
    __syncthreads();
}

// ================= conv core: implicit GEMM, 16x16x32 bf16 MFMA, bf16x3 split =================
// A: [M][CIP] activations (hi/lo) from global; B: LDS fragment-order weights.
template<int CIP, int NCH, int NCOT, int IH>
__device__ __forceinline__ void conv_core(
        const __bf16* __restrict__ Ahi, const __bf16* __restrict__ Alo,
        const __bf16* sWh, const __bf16* sWl,
        int mtile, f32x4 acc[NCOT])
{
    const int IW = 128;
    constexpr int NTAP = (CIP == 32) ? NCH : NCH * 4;
    int lane = threadIdx.x & 63;
    int n16  = lane & 15;
    int quad = lane >> 4;
    int p0  = mtile * 16;
    int b   = p0 / (IH * IW);
    int rem = p0 - b * (IH * IW);
    int ty  = rem >> 7;
    int tx0 = rem & 127;
    #pragma unroll
    for (int c = 0; c < NCH; ++c) {
        int tap = (CIP == 32) ? c : (c * 4 + quad);
        int dy = tap / 3 - 1;
        int dx = tap % 3 - 1;
        int yy = ty + dy;
        int xx = tx0 + n16 + dx;
        bool valid = (tap < 9) && (yy >= 0) && (yy < IH) && (xx >= 0) && (xx < IW);
        bf16x8 a_h = {};
        bf16x8 a_l = {};
        if (valid) {
            size_t off = (size_t)(b * IH * IW + yy * IW + xx) * CIP
                       + ((CIP == 32) ? (quad * 8) : 0);
            a_h = *(const bf16x8*)(Ahi + off);
            a_l = *(const bf16x8*)(Alo + off);
        }
        #pragma unroll
        for (int ct = 0; ct < NCOT; ++ct) {
            int woff8 = (CIP == 32) ? ((ct * NTAP + c) * 64 + lane)
                                    : ((ct * NTAP + tap) * 16 + n16);
            bf16x8 b_h = *(const bf16x8*)(sWh + woff8 * 8);
            bf16x8 b_l = *(const bf16x8*)(sWl + woff8 * 8);
            acc[ct] = __builtin_amdgcn_mfma_f32_16x16x32_bf16(a_h, b_h, acc[ct], 0, 0, 0);
            acc[ct] = __builtin_amdgcn_mfma_f32_16x16x32_bf16(a_h, b_l, acc[ct], 0, 0, 0);
            acc[ct] = __builtin_amdgcn_mfma_f32_16x16x32_bf16(a_l, b_h, acc[ct], 0, 0, 0);
        }
    }
}

// conv1 / conv2: bias + relu -> hid hi/lo [M][32]   (grid covers Mtiles exactly)
template<int CIP, int NCH, int IH>
__global__ __launch_bounds__(256) void conv_ab_k(
        const __bf16* __restrict__ Ahi, const __bf16* __restrict__ Alo,
        const __bf16* __restrict__ Whi, const __bf16* __restrict__ Wlo,
        const float* __restrict__ bias,
        __bf16* __restrict__ Ohi, __bf16* __restrict__ Olo, int Mtiles)
{
    constexpr int NTAP = (CIP == 32) ? NCH : NCH * 4;
    constexpr int TOT  = 2 * NTAP * ((CIP == 32) ? 64 : 16) * 8;
    __shared__ __align__(16) __bf16 sWh[TOT];
    __shared__ __align__(16) __bf16 sWl[TOT];
    stage_w<CIP, NCH, 2>(Whi, Wlo, sWh, sWl);
    int wid = (blockIdx.x * 256 + threadIdx.x) >> 6;
    f32x4 acc[2] = {};
    conv_core<CIP, NCH, 2, IH>(Ahi, Alo, sWh, sWl, wid, acc);
    int lane = threadIdx.x & 63;
    int n16 = lane & 15;
    int quad = lane >> 4;
    #pragma unroll
    for (int ct = 0; ct < 2; ++ct) {
        float bv = bias[ct * 16 + n16];
        #pragma unroll
        for (int r = 0; r < 4; ++r) {
            float v = acc[ct][r] + bv;
            v = fmaxf(v, 0.f);
            int m = wid * 16 + quad * 4 + r;
            split_store(Ohi, Olo, m * 32 + ct * 16 + n16, v);
        }
    }
}

// conv3 dual: dual_f += sigma*(acc+bias); write cat_d ch0-4 hi/lo; dual0 packed (co==0)
template<int IH>
__global__ __launch_bounds__(256) void conv_c_dual_k(
        const __bf16* __restrict__ Ahi, const __bf16* __restrict__ Alo,
        const __bf16* __restrict__ Whi, const __bf16* __restrict__ Wlo,
        const float* __restrict__ bias, const float* __restrict__ sigma_p,
        float* __restrict__ dual_f, __bf16* __restrict__ cat_hi, __bf16* __restrict__ cat_lo,
        float* __restrict__ dual0, int Mtiles)
{
    constexpr int TOT = 1 * 9 * 64 * 8;
    __shared__ __align__(16) __bf16 sWh[TOT];
    __shared__ __align__(16) __bf16 sWl[TOT];
    stage_w<32, 9, 1>(Whi, Wlo, sWh, sWl);
    int wid = (blockIdx.x * 256 + threadIdx.x) >> 6;
    f32x4 acc[1] = {};
    conv_core<32, 9, 1, IH>(Ahi, Alo, sWh, sWl, wid, acc);
    int lane = threadIdx.x & 63;
    int n16 = lane & 15;
    int quad = lane >> 4;
    if (n16 < 5) {
        float sg = *sigma_p;
        float bv = bias[n16];
        #pragma unroll
        for (int r = 0; r < 4; ++r) {
            int m = wid * 16 + quad * 4 + r;
            float v = acc[0][r] + bv;
            float dn = dual_f[m * 5 + n16] + sg * v;
            dual_f[m * 5 + n16] = dn;
            split_store(cat_hi, cat_lo, m * 8 + n16, dn);
            if (n16 == 0) dual0[m] = dn;
        }
    }
}

// conv3 primal: primal update + pbar ch1
template<int IH>
__global__ __launch_bounds__(256) void conv_c_prim_k(
        const __bf16* __restrict__ Ahi, const __bf16* __restrict__ Alo,
        const __bf16* __restrict__ Whi, const __bf16* __restrict__ Wlo,
        const float* __restrict__ bias, const float* __restrict__ tau_p,
        const float* __restrict__ theta_p,
        float* __restrict__ primal_f, __bf16* __restrict__ cat_hi, __bf16* __restrict__ cat_lo,
        float* __restrict__ pbar1, int Mtiles)
{
    constexpr int TOT = 1 * 9 * 64 * 8;
    __shared__ __align__(16) __bf16 sWh[TOT];
    __shared__ __align__(16) __bf16 sWl[TOT];
    stage_w<32, 9, 1>(Whi, Wlo, sWh, sWl);
    int wid = (blockIdx.x * 256 + threadIdx.x) >> 6;
    f32x4 acc[1] = {};
    conv_core<32, 9, 1, IH>(Ahi, Alo, sWh, sWl, wid, acc);
    int lane = threadIdx.x & 63;
    int n16 = lane & 15;
    int quad = lane >> 4;
    if (n16 < 5) {
        float ta = *tau_p;
        float th = *theta_p;
        float bv = bias[n16];
        #pragma unroll
        for (int r = 0; r < 4; ++r) {
            int m = wid * 16 + quad * 4 + r;
            float v = acc[0][r] + bv;
            float pold = primal_f[m * 5 + n16];
            float pn = pold + ta * v;
            primal_f[m * 5 + n16] = pn;
            split_store(cat_hi, cat_lo, m * 8 + n16, pn);
            if (n16 == 1) pbar1[m] = pn + th * (pn - pold);
        }
    }
}

// ================= Radon forward: fused t-split x4 + LDS reduce + direct cat store ========
__global__ __launch_bounds__(256) void radon_fwd_fused_k(const float* __restrict__ img,
                                                         const float* __restrict__ trig,
                                                         __bf16* __restrict__ cat_hi,
                                                         __bf16* __restrict__ cat_lo)
{
    __shared__ float red[256];
    int tid = threadIdx.x;
    int q = tid >> 6;
    int j = tid & 63;
    int pix = blockIdx.x * 64 + j;
    int d = pix & 127;
    int b = pix / (AANG * DDET);
    int a = (pix - b * AANG * DDET) >> 7;
    float c  = trig[a];
    float sn = trig[AANG + a];
    float s = (float)d - 63.5f;
    float A = s * c + 63.5f;    // xi = A - t*sn
    float C = s * sn + 63.5f;   // yi = C + t*c
    float tlo = -1e30f, thi = 1e30f;
    if (sn > 1e-6f) {
        tlo = (A - 128.f) / sn;
        thi = (A + 1.f) / sn;
    }
    if (c > 1e-6f) {
        tlo = fmaxf(tlo, (-1.f - C) / c);
        thi = fminf(thi, (128.f - C) / c);
    } else if (c < -1e-6f) {
        tlo = fmaxf(tlo, (128.f - C) / c);
        thi = fminf(thi, (-1.f - C) / c);
    }
    float flo = fmaxf(fminf(tlo + 90.5f, 300.f), -300.f);
    float fhi = fmaxf(fminf(thi + 90.5f, 300.f), -300.f);
    int clo = (int)floorf(flo) - 1;
    int chi = (int)floorf(fhi) + 2;
    int t0 = q * 46;
    int t1 = t0 + 46 < TSTEP ? t0 + 46 : TSTEP;
    if (clo > t0) t0 = clo;
    if (chi < t1) t1 = chi;
    const float* ib = img + b * (HHH * WWW);
    float acc = 0.f;
    for (int tt = t0; tt < t1; ++tt) {
        float t = (float)tt - 90.5f;
        float xi = A - t * sn;
        float yi = C + t * c;
        float x0f = floorf(xi), y0f = floorf(yi);
        float wx = xi - x0f, wy = yi - y0f;
        int x0 = (int)x0f, y0 = (int)y0f;
        int x1 = x0 + 1, y1 = y0 + 1;
        bool xv0 = (x0 >= 0) & (x0 < WWW);
        bool xv1 = (x1 >= 0) & (x1 < WWW);
        bool yv0 = (y0 >= 0) & (y0 < HHH);
        bool yv1 = (y1 >= 0) & (y1 < HHH);
        float v00 = (yv0 & xv0) ? ib[y0 * WWW + x0] : 0.f;
        float v01 = (yv0 & xv1) ? ib[y0 * WWW + x1] : 0.f;
        float v10 = (yv1 & xv0) ? ib[y1 * WWW + x0] : 0.f;
        float v11 = (yv1 & xv1) ? ib[y1 * WWW + x1] : 0.f;
        acc += v00 * (1.f - wy) * (1.f - wx) + v01 * (1.f - wy) * wx
             + v10 * wy * (1.f - wx) + v11 * wy * wx;
    }
    red[tid] = acc;
    __syncthreads();
    if (tid < 64) {
        int p2 = blockIdx.x * 64 + tid;
        float v = (red[tid] + red[tid + 64] + red[tid + 128] + red[tid + 192]) * INV_OPN;
        split_store(cat_hi, cat_lo, p2 * 8 + 5, v);
    }
}

// ================= Radon adjoint: fused a-split x2 + LDS reduce + direct cat store ========
__global__ __launch_bounds__(256) void radon_adj_fused_k(const float* __restrict__ sino0,
                                                         const float* __restrict__ trig,
                                                         __bf16* __restrict__ cat_hi,
                                                         __bf16* __restrict__ cat_lo)
{
    __shared__ float cs[AANG], ss[AANG];
    __shared__ float red[256];
    int tid = threadIdx.x;
    if (tid < AANG) {
        cs[tid] = trig[tid];
        ss[tid] = trig[AANG + tid];
    }
    __syncthreads();
    int h = tid >> 7;
    int j = tid & 127;
    int pix = blockIdx.x * 128 + j;
    int x = pix & 127;
    int yv = (pix >> 7) & 127;
    int b = pix >> 14;
    float px = (float)x - 63.5f;
    float py = (float)yv - 63.5f;
    const float* sb = sino0 + b * (AANG * DDET);
    float acc = 0.f;
    int a0 = h * 48;
    for (int a = a0; a < a0 + 48; ++a) {
        float det = px * cs[a] + py * ss[a] + 63.5f;
        float dh = floorf(det);
        float w = det - dh;
        int d0 = (int)dh;
        int d1 = d0 + 1;
        float v0 = (d0 >= 0 && d0 < DDET) ? sb[a * DDET + d0] : 0.f;
        float v1 = (d1 >= 0 && d1 < DDET) ? sb[a * DDET + d1] : 0.f;
        acc += v0 * (1.f - w) + v1 * w;
    }
    red[tid] = acc;
    __syncthreads();
    if (tid < 128) {
        float v = (red[tid] + red[tid + 128]) * INV_OPN;
        split_store(cat_hi, cat_lo, (blockIdx.x * 128 + tid) * 8 + 5, v);
    }
}

// ================= setup: trig table + weight transpose/split + y cat store ===============
__global__ __launch_bounds__(256) void prep_all_k(
        const float* __restrict__ dw1, const float* __restrict__ dw2, const float* __restrict__ dw3,
        const float* __restrict__ pw1, const float* __restrict__ pw2, const float* __restrict__ pw3,
        const float* __restrict__ y,
        __bf16* __restrict__ wT, float* __restrict__ trig,
        __bf16* __restrict__ cat_d_hi, __bf16* __restrict__ cat_d_lo)
{
    __bf16* d1h = wT;            __bf16* d1l = d1h + 3072;
    __bf16* d2h = d1l + 3072;    __bf16* d2l = d2h + 9216;
    __bf16* d3h = d2l + 9216;    __bf16* d3l = d3h + 4608;
    __bf16* p1h = d3l + 4608;    __bf16* p1l = p1h + 3072;
    __bf16* p2h = p1l + 3072;    __bf16* p2l = p2h + 9216;
    __bf16* p3h = p2l + 9216;    __bf16* p3l = p3h + 4608;
    int i = blockIdx.x * 256 + threadIdx.x;
    if (i < AANG) {
        double ang = (double)i * M_PI / (double)AANG;
        trig[i] = (float)cos(ang);
        trig[AANG + i] = (float)sin(ang);
        return;
    }
    i -= AANG;
    if (i < 2016) {                 // dw1: CI=7 CO=32 -> [12][32][8]
        int co = i & 31; int r = i >> 5; int ci = r % 7; int tap = r / 7;
        split_store(d1h, d1l, (tap * 32 + co) * 8 + ci, dw1[i]);
        return;
    }
    i -= 2016;
    if (i < 9216) {                 // dw2: CI=32 CO=32 -> [9][32][32]
        int co = i & 31; int r = i >> 5; int ci = r & 31; int tap = r >> 5;
        split_store(d2h, d2l, (tap * 32 + co) * 32 + ci, dw2[i]);
        return;
    }
    i -= 9216;
    if (i < 1440) {                 // dw3: CI=32 CO=5 -> [9][16][32]
        int co = i % 5; int r = i / 5; int ci = r & 31; int tap = r >> 5;
        split_store(d3h, d3l, (tap * 16 + co) * 32 + ci, dw3[i]);
        return;
    }
    i -= 1440;
    if (i < 1728) {                 // pw1: CI=6 CO=32 -> [12][32][8]
        int co = i & 31; int r = i >> 5; int ci = r % 6; int tap = r / 6;
        split_store(p1h, p1l, (tap * 32 + co) * 8 + ci, pw1[i]);
        return;
    }
    i -= 1728;
    if (i < 9216) {                 // pw2
        int co = i & 31; int r = i >> 5; int ci = r & 31; int tap = r >> 5;
        split_store(p2h, p2l, (tap * 32 + co) * 32 + ci, pw2[i]);
        return;
    }
    i -= 9216;
    if (i < 1440) {                 // pw3
        int co = i % 5; int r = i / 5; int ci = r & 31; int tap = r >> 5;
        split_store(p3h, p3l, (tap * 16 + co) * 32 + ci, pw3[i]);
        return;
    }
    i -= 1440;
    if (i < M_D) {                  // y -> cat_d ch6
        split_store(cat_d_hi, cat_d_lo, i * 8 + 6, y[i]);
        return;
    }
}

__global__ __launch_bounds__(256) void extract_k(const float* __restrict__ primal_f,
                                                 float* __restrict__ out)
{
    int pix = blockIdx.x * 256 + threadIdx.x;
    if (pix >= M_P) return;
    out[pix] = primal_f[pix * 5];
}

extern "C" void kernel_launch(void* const* d_in, const int* in_sizes, int n_in,
                              void* d_out, int out_size, void* d_ws, size_t ws_size,
                              hipStream_t stream) {
    const float* y     = (const float*)d_in[0];
    const float* sigma = (const float*)d_in[1];
    const float* tau   = (const float*)d_in[2];
    const float* theta = (const float*)d_in[3];
    const float* dw1 = (const float*)d_in[4];
    const float* db1 = (const float*)d_in[5];
    const float* dw2 = (const float*)d_in[6];
    const float* db2 = (const float*)d_in[7];
    const float* dw3 = (const float*)d_in[8];
    const float* db3 = (const float*)d_in[9];
    const float* pw1 = (const float*)d_in[10];
    const float* pb1 = (const float*)d_in[11];
    const float* pw2 = (const float*)d_in[12];
    const float* pb2 = (const float*)d_in[13];
    const float* pw3 = (const float*)d_in[14];
    const float* pb3 = (const float*)d_in[15];

    float* ws = (float*)d_ws;
    float* primal_f = ws;                    // M_P*5
    float* dual_f   = primal_f + M_P * 5;    // M_D*5
    float* pbar1    = dual_f + M_D * 5;      // M_P
    __bf16* bf = (__bf16*)(pbar1 + M_P);
    __bf16* cat_d_hi = bf;                   // M_D*8
    __bf16* cat_d_lo = cat_d_hi + M_D * 8;
    __bf16* cat_p_hi = cat_d_lo + M_D * 8;   // M_P*8
    __bf16* cat_p_lo = cat_p_hi + M_P * 8;
    __bf16* wT       = cat_p_lo + M_P * 8;   // 67584
    float* trig     = (float*)(wT + 67584);  // 192
    float* dual0    = trig + 192;            // M_D
    __bf16* hidA_hi = (__bf16*)(dual0 + M_D);
    __bf16* hidA_lo = hidA_hi + M_P * 32;
    __bf16* hidB_hi = hidA_lo + M_P * 32;
    __bf16* hidB_lo = hidB_hi + M_P * 32;

    __bf16* d1h = wT;            __bf16* d1l = d1h + 3072;
    __bf16* d2h = d1l + 3072;    __bf16* d2l = d2h + 9216;
    __bf16* d3h = d2l + 9216;    __bf16* d3l = d3h + 4608;
    __bf16* p1h = d3l + 4608;    __bf16* p1l = p1h + 3072;
    __bf16* p2h = p1l + 3072;    __bf16* p2l = p2h + 9216;
    __bf16* p3h = p2l + 9216;    __bf16* p3l = p3h + 4608;

    size_t zbytes = (size_t)(M_P * 5 + M_D * 5 + M_P) * 4
                  + (size_t)(M_D * 16 + M_P * 16 + 67584) * 2;
    hipMemsetAsync(ws, 0, zbytes, stream);

    {
        int items = AANG + 25056 + M_D;
        prep_all_k<<<(items + 255) / 256, 256, 0, stream>>>(dw1, dw2, dw3, pw1, pw2, pw3, y,
                                                            wT, trig, cat_d_hi, cat_d_lo);
    }

    const int MT_D = M_D / 16;   // 3072
    const int MT_P = M_P / 16;   // 4096

    for (int it = 0; it < 10; ++it) {
        radon_fwd_fused_k<<<M_D / 64, 256, 0, stream>>>(pbar1, trig, cat_d_hi, cat_d_lo);
        conv_ab_k<8, 3, AANG><<<MT_D / 4, 256, 0, stream>>>(cat_d_hi, cat_d_lo, d1h, d1l, db1, hidA_hi, hidA_lo, MT_D);
        conv_ab_k<32, 9, AANG><<<MT_D / 4, 256, 0, stream>>>(hidA_hi, hidA_lo, d2h, d2l, db2, hidB_hi, hidB_lo, MT_D);
        conv_c_dual_k<AANG><<<MT_D / 4, 256, 0, stream>>>(hidB_hi, hidB_lo, d3h, d3l, db3, sigma, dual_f, cat_d_hi, cat_d_lo, dual0, MT_D);
        radon_adj_fused_k<<<M_P / 128, 256, 0, stream>>>(dual0, trig, cat_p_hi, cat_p_lo);
        conv_ab_k<8, 3, HHH><<<MT_P / 4, 256, 0, stream>>>(cat_p_hi, cat_p_lo, p1h, p1l, pb1, hidA_hi, hidA_lo, MT_P);
        conv_ab_k<32, 9, HHH><<<MT_P / 4, 256, 0, stream>>>(hidA_hi, hidA_lo, p2h, p2l, pb2, hidB_hi, hidB_lo, MT_P);
        conv_c_prim_k<HHH><<<MT_P / 4, 256, 0, stream>>>(hidB_hi, hidB_lo, p3h, p3l, pb3, tau, theta, primal_f, cat_p_hi, cat_p_lo, pbar1, MT_P);
    }
    extract_k<<<M_P / 256, 256, 0, stream>>>(primal_f, (float*)d_out);
}